// Round 1
// baseline (1305.452 us; speedup 1.0000x reference)
//
#include <hip/hip_runtime.h>

// Problem constants (from reference): 16 clouds x 4096 pts, sample 1024, D=512
#define N_PER   4096
#define M_SAMP  1024
#define B_CL    16
#define D_FEAT  512
#define TPB     256
#define PPT     (N_PER / TPB)   // 16 points per thread (blocked: thread t owns t*16..t*16+15)

// ---------------------------------------------------------------------------
// FPS: one workgroup per cloud. pos staged in LDS (float4-padded), per-thread
// dist kept in registers. Exact replication of jnp semantics:
//   d2 = ((dx*dx + dy*dy) + dz*dz)  in f32, no FMA contraction
//   argmax = first occurrence of max  (tie-break: greater val, else smaller idx)
// ---------------------------------------------------------------------------
__global__ __launch_bounds__(TPB) void fps_kernel(const float* __restrict__ pos,
                                                  int* __restrict__ sidx) {
    __shared__ float4 spos[N_PER];      // 64 KiB
    __shared__ float  swv[2][4];        // double-buffered cross-wave winners
    __shared__ int    swi[2][4];

    const int cloud = blockIdx.x;
    const int tid   = threadIdx.x;
    const float* posb = pos + (size_t)cloud * N_PER * 3;

    // stage cloud positions into LDS (coalesced global reads)
    for (int i = tid; i < N_PER * 3; i += TPB) {
        int p = i / 3, c = i - p * 3;
        ((float*)&spos[p])[c] = posb[i];
    }
    __syncthreads();

    // preload my 16 points + init dist
    float px[PPT], py[PPT], pz[PPT], dist[PPT];
    const int base = tid * PPT;
#pragma unroll
    for (int j = 0; j < PPT; ++j) {
        float4 v = spos[base + j];
        px[j] = v.x; py[j] = v.y; pz[j] = v.z;
        dist[j] = 1e30f;
    }

    int last = 0;
    if (tid == 0) sidx[cloud * M_SAMP] = 0;   // deterministic start at local 0

    const int wave = tid >> 6;
    const int lane = tid & 63;

    for (int s = 1; s < M_SAMP; ++s) {
        float4 lp = spos[last];               // broadcast LDS read (no conflict)

        float bv = -1.0f;                     // all dist >= 0, so always beaten
        int   bi = 0;
#pragma unroll
        for (int j = 0; j < PPT; ++j) {
            float dx = __fsub_rn(px[j], lp.x);
            float dy = __fsub_rn(py[j], lp.y);
            float dz = __fsub_rn(pz[j], lp.z);
            float d2 = __fadd_rn(__fadd_rn(__fmul_rn(dx, dx), __fmul_rn(dy, dy)),
                                 __fmul_rn(dz, dz));
            float dn = fminf(dist[j], d2);
            dist[j] = dn;
            // ascending j + strictly-greater keeps first occurrence
            if (dn > bv) { bv = dn; bi = base + j; }
        }

        // 64-lane butterfly argmax (val desc, idx asc tie-break)
#pragma unroll
        for (int m = 1; m < 64; m <<= 1) {
            float v2 = __shfl_xor(bv, m, 64);
            int   i2 = __shfl_xor(bi, m, 64);
            if (v2 > bv || (v2 == bv && i2 < bi)) { bv = v2; bi = i2; }
        }

        // cross-wave merge via LDS (double-buffered, single barrier per step)
        const int buf = s & 1;
        if (lane == 0) { swv[buf][wave] = bv; swi[buf][wave] = bi; }
        __syncthreads();
        float fv = swv[buf][0];
        int   fi = swi[buf][0];
#pragma unroll
        for (int w = 1; w < 4; ++w) {
            float v2 = swv[buf][w];
            int   i2 = swi[buf][w];
            if (v2 > fv || (v2 == fv && i2 < fi)) { fv = v2; fi = i2; }
        }
        last = fi;
        if (tid == 0) sidx[cloud * M_SAMP + s] = last;  // local idx; globalized in gather
    }
}

// ---------------------------------------------------------------------------
// Gather x rows: out[r][:] = x[g][:], float4-vectorized. 16384 rows x 128 f4.
// sidx holds LOCAL per-cloud indices; globalize with cloud offset r/M*N_PER.
// ---------------------------------------------------------------------------
__global__ __launch_bounds__(TPB) void gather_x_kernel(const float4* __restrict__ x4,
                                                       const int* __restrict__ sidx,
                                                       float4* __restrict__ out4) {
    int id = blockIdx.x * TPB + threadIdx.x;     // 0 .. 16384*128-1
    int r  = id >> 7;                            // row in output
    int c  = id & 127;                           // float4 column
    int g  = sidx[r] + (r >> 10 << 12);          // + (r/1024)*4096 global offset
    out4[id] = x4[(size_t)g * (D_FEAT / 4) + c];
}

// ---------------------------------------------------------------------------
// Gather pos (3 f32/row) and batch (as float). 16384 threads.
// ---------------------------------------------------------------------------
__global__ __launch_bounds__(TPB) void gather_pb_kernel(const float* __restrict__ pos,
                                                        const int* __restrict__ batch,
                                                        const int* __restrict__ sidx,
                                                        float* __restrict__ out_pos,
                                                        float* __restrict__ out_batch) {
    int r = blockIdx.x * TPB + threadIdx.x;      // 0 .. 16383
    int g = sidx[r] + (r >> 10 << 12);
    out_pos[r * 3 + 0] = pos[g * 3 + 0];
    out_pos[r * 3 + 1] = pos[g * 3 + 1];
    out_pos[r * 3 + 2] = pos[g * 3 + 2];
    out_batch[r] = (float)batch[g];
}

extern "C" void kernel_launch(void* const* d_in, const int* in_sizes, int n_in,
                              void* d_out, int out_size, void* d_ws, size_t ws_size,
                              hipStream_t stream) {
    const float* x     = (const float*)d_in[0];   // [65536,512] f32
    const float* pos   = (const float*)d_in[1];   // [65536,3]   f32
    const int*   batch = (const int*)d_in[2];     // [65536]     i32

    int* sidx = (int*)d_ws;                       // [16384] local sampled indices

    float* out   = (float*)d_out;
    float* out_x = out;                                            // 16384*512
    float* out_p = out + (size_t)B_CL * M_SAMP * D_FEAT;           // 16384*3
    float* out_b = out_p + (size_t)B_CL * M_SAMP * 3;              // 16384

    // 1) FPS: 16 blocks (one per cloud)
    fps_kernel<<<B_CL, TPB, 0, stream>>>(pos, sidx);

    // 2) x gather: 16384 rows * 128 float4 / 256 threads = 8192 blocks
    gather_x_kernel<<<(B_CL * M_SAMP * (D_FEAT / 4)) / TPB, TPB, 0, stream>>>(
        (const float4*)x, sidx, (float4*)out_x);

    // 3) pos + batch gather: 16384 / 256 = 64 blocks
    gather_pb_kernel<<<(B_CL * M_SAMP) / TPB, TPB, 0, stream>>>(
        pos, batch, sidx, out_p, out_b);
}